// Round 6
// baseline (73.816 us; speedup 1.0000x reference)
//
#include <hip/hip_runtime.h>
#include <hip/hip_bf16.h>

typedef __hip_bfloat16 bf16;
typedef __attribute__((ext_vector_type(8))) short bf16x8;   // 8 bf16 = 4 VGPR
typedef __attribute__((ext_vector_type(4))) float f32x4;

#define MFMA16(a, b, c) __builtin_amdgcn_mfma_f32_16x16x32_bf16((a), (b), (c), 0, 0, 0)

// ---- constants ----
// B=2, S=2048, D=768, HD=64, NH=12, NKV=4, GROUPS=3, WINDOW=384, theta=1e4, eps=1e-6
// I/O fp32; bf16 intermediates in ws; V stored transposed [b][kv][d][s].

__device__ __forceinline__ void st4bf(bf16* p, float4 v) {
    bf16 t[4];
    t[0] = __float2bfloat16(v.x); t[1] = __float2bfloat16(v.y);
    t[2] = __float2bfloat16(v.z); t[3] = __float2bfloat16(v.w);
    *reinterpret_cast<uint2*>(p) = *reinterpret_cast<const uint2*>(t);
}

// ============ Kernel 0: fp32->bf16 conversion of hs + weights, and RoPE table ======
__global__ __launch_bounds__(256) void k_prep(
    const float* __restrict__ hs, const float* __restrict__ qw,
    const float* __restrict__ kw, const float* __restrict__ vw,
    const float* __restrict__ ow,
    bf16* __restrict__ hsb, bf16* __restrict__ qwb, bf16* __restrict__ kwb,
    bf16* __restrict__ vwb, bf16* __restrict__ owb, float2* __restrict__ tab)
{
    const int bid = blockIdx.x, tid = threadIdx.x;
    const float* src; bf16* dst; int rel;
    if (bid < 3072)      { src = hs; dst = hsb; rel = bid; }
    else if (bid < 3648) { src = qw; dst = qwb; rel = bid - 3072; }
    else if (bid < 3840) { src = kw; dst = kwb; rel = bid - 3648; }
    else if (bid < 4032) { src = vw; dst = vwb; rel = bid - 3840; }
    else if (bid < 4608) { src = ow; dst = owb; rel = bid - 4032; }
    else {
        int i = (bid - 4608) * 256 + tid;          // 65536 entries
        int f = i & 31;
        float ang = (float)(i >> 5) * expf(-(float)f * 0.28782313662425572f);  // ln(1e4)/32
        float sn, cs; sincosf(ang, &sn, &cs);
        tab[i] = make_float2(cs, sn);
        return;
    }
    int i = (rel * 256 + tid) * 4;
    float4 v = *reinterpret_cast<const float4*>(src + i);
    st4bf(dst + i, v);
}

// ================= Kernel 1: MFMA QKV GEMM + RMSNorm + RoPE (BM=128) ============
// grid (32 m-tiles, 20 n-blocks): 0-11 q heads, 12-15 k heads, 16-19 v heads.
// 4 waves; wave w owns rows [32w, 32w+32) as two 16-row fragments.
__global__ __launch_bounds__(256) void k_qkv(
    const bf16* __restrict__ hsb, const bf16* __restrict__ qwb,
    const bf16* __restrict__ kwb, const bf16* __restrict__ vwb,
    const float* __restrict__ qln, const float* __restrict__ kln,
    const float2* __restrict__ tab,
    bf16* __restrict__ qo, bf16* __restrict__ ko, bf16* __restrict__ vto)
{
    __shared__ bf16 As[2][128 * 72];
    __shared__ bf16 Bs[2][64 * 72];
    const int tid = threadIdx.x;
    const int w = tid >> 6, l = tid & 63;
    const int lm = l & 15, lg = l >> 4;
    const int m0 = blockIdx.x * 128;
    const int nblk = blockIdx.y;

    const bf16* wsrc; int wrow0, kind, head;
    if (nblk < 12)      { wsrc = qwb; wrow0 = nblk * 64;        kind = 0; head = nblk; }
    else if (nblk < 16) { wsrc = kwb; wrow0 = (nblk - 12) * 64; kind = 1; head = nblk - 12; }
    else                { wsrc = vwb; wrow0 = (nblk - 16) * 64; kind = 2; head = nblk - 16; }

    const int sr = tid >> 2, sc = (tid & 3) * 16;
    const bf16* aptr0 = hsb  + (size_t)(m0 + sr) * 768 + sc;        // rows [0,64)
    const bf16* aptr1 = hsb  + (size_t)(m0 + 64 + sr) * 768 + sc;   // rows [64,128)
    const bf16* bptr  = wsrc + (size_t)(wrow0 + sr) * 768 + sc;

    bf16x8 ra[4], rb[2];
    ra[0] = *(const bf16x8*)(aptr0);
    ra[1] = *(const bf16x8*)(aptr0 + 8);
    ra[2] = *(const bf16x8*)(aptr1);
    ra[3] = *(const bf16x8*)(aptr1 + 8);
    rb[0] = *(const bf16x8*)(bptr);
    rb[1] = *(const bf16x8*)(bptr + 8);
    *(bf16x8*)(&As[0][sr * 72 + sc])            = ra[0];
    *(bf16x8*)(&As[0][sr * 72 + sc + 8])        = ra[1];
    *(bf16x8*)(&As[0][(64 + sr) * 72 + sc])     = ra[2];
    *(bf16x8*)(&As[0][(64 + sr) * 72 + sc + 8]) = ra[3];
    *(bf16x8*)(&Bs[0][sr * 72 + sc])            = rb[0];
    *(bf16x8*)(&Bs[0][sr * 72 + sc + 8])        = rb[1];
    __syncthreads();

    f32x4 acc[2][4] = {};
    for (int t = 0; t < 12; ++t) {
        const int p = t & 1;
        if (t < 11) {
            const int off = (t + 1) * 64;
            ra[0] = *(const bf16x8*)(aptr0 + off);
            ra[1] = *(const bf16x8*)(aptr0 + off + 8);
            ra[2] = *(const bf16x8*)(aptr1 + off);
            ra[3] = *(const bf16x8*)(aptr1 + off + 8);
            rb[0] = *(const bf16x8*)(bptr + off);
            rb[1] = *(const bf16x8*)(bptr + off + 8);
        }
        #pragma unroll
        for (int kk = 0; kk < 2; ++kk) {
            bf16x8 a0 = *(const bf16x8*)(&As[p][(w * 32 + lm) * 72 + kk * 32 + lg * 8]);
            bf16x8 a1 = *(const bf16x8*)(&As[p][(w * 32 + 16 + lm) * 72 + kk * 32 + lg * 8]);
            #pragma unroll
            for (int ct = 0; ct < 4; ++ct) {
                bf16x8 bfr = *(const bf16x8*)(&Bs[p][(ct * 16 + lm) * 72 + kk * 32 + lg * 8]);
                acc[0][ct] = MFMA16(a0, bfr, acc[0][ct]);
                acc[1][ct] = MFMA16(a1, bfr, acc[1][ct]);
            }
        }
        if (t < 11) {
            __syncthreads();
            *(bf16x8*)(&As[p ^ 1][sr * 72 + sc])            = ra[0];
            *(bf16x8*)(&As[p ^ 1][sr * 72 + sc + 8])        = ra[1];
            *(bf16x8*)(&As[p ^ 1][(64 + sr) * 72 + sc])     = ra[2];
            *(bf16x8*)(&As[p ^ 1][(64 + sr) * 72 + sc + 8]) = ra[3];
            *(bf16x8*)(&Bs[p ^ 1][sr * 72 + sc])            = rb[0];
            *(bf16x8*)(&Bs[p ^ 1][sr * 72 + sc + 8])        = rb[1];
            __syncthreads();
        }
    }

    const int b  = m0 >> 11;
    const int s0 = m0 & 2047;

    if (kind == 2) {  // V: write TRANSPOSED [b][kv][d][s]
        bf16* base = vto + (size_t)(b * 4 + head) * 64 * 2048;
        #pragma unroll
        for (int m = 0; m < 2; ++m)
            #pragma unroll
            for (int r = 0; r < 4; ++r) {
                const int s = s0 + w * 32 + m * 16 + lg * 4 + r;
                #pragma unroll
                for (int ct = 0; ct < 4; ++ct)
                    base[(size_t)(ct * 16 + lm) * 2048 + s] = __float2bfloat16(acc[m][ct][r]);
            }
        return;
    }

    const float* ln = (kind == 0) ? qln : kln;
    float lw[4];
    #pragma unroll
    for (int ct = 0; ct < 4; ++ct) lw[ct] = ln[ct * 16 + lm];

    bf16* base = (kind == 0) ? qo + ((size_t)(b * 12 + head) * 2048 + s0) * 64
                             : ko + ((size_t)(b * 4  + head) * 2048 + s0) * 64;
    #pragma unroll
    for (int m = 0; m < 2; ++m)
        #pragma unroll
        for (int r = 0; r < 4; ++r) {
            float n0 = acc[m][0][r], n1 = acc[m][1][r], n2 = acc[m][2][r], n3 = acc[m][3][r];
            float ss = n0 * n0 + n1 * n1 + n2 * n2 + n3 * n3;
            ss += __shfl_xor(ss, 1);
            ss += __shfl_xor(ss, 2);
            ss += __shfl_xor(ss, 4);
            ss += __shfl_xor(ss, 8);
            float rms = rsqrtf(ss * (1.0f / 64.0f) + 1e-6f);
            n0 *= rms * lw[0]; n1 *= rms * lw[1]; n2 *= rms * lw[2]; n3 *= rms * lw[3];
            const int row = w * 32 + m * 16 + lg * 4 + r;
            const float2* tp = tab + (size_t)(s0 + row) * 32;
            float2 t0 = tp[lm], t1 = tp[lm + 16];
            bf16* dst = base + (size_t)row * 64;
            dst[lm]      = __float2bfloat16(n0 * t0.x - n2 * t0.y);
            dst[lm + 16] = __float2bfloat16(n1 * t1.x - n3 * t1.y);
            dst[lm + 32] = __float2bfloat16(n2 * t0.x + n0 * t0.y);
            dst[lm + 48] = __float2bfloat16(n3 * t1.x + n1 * t1.y);
        }
}

// ================= Kernel 2: MFMA sliding-window attention (dbuf K/V, exp2) ======
__global__ __launch_bounds__(256) void k_attn(
    const bf16* __restrict__ qi, const bf16* __restrict__ ki,
    const bf16* __restrict__ vti, bf16* __restrict__ ao)
{
    __shared__ bf16 Ks[2][64 * 72];   // [key][d]
    __shared__ bf16 Vs[2][64 * 72];   // [d][key]
    __shared__ bf16 Ps[64 * 72];      // per-wave-private rows
    const int tid = threadIdx.x;
    const int w = tid >> 6, l = tid & 63;
    const int lm = l & 15, lg = l >> 4;
    const int qb = blockIdx.x, h = blockIdx.y, b = blockIdx.z;
    const int kv = h / 3;
    const int q0 = qb * 64;
    const float SCL2 = 0.18033688011117042f;   // 0.125 * log2(e); softmax in exp2-space

    const bf16* qbase = qi + ((size_t)((b * 12 + h) * 2048 + q0 + w * 16 + lm)) * 64 + lg * 8;
    bf16x8 qf0 = *(const bf16x8*)(qbase);
    bf16x8 qf1 = *(const bf16x8*)(qbase + 32);

    f32x4 oacc[4] = {};
    float m_[4], l_[4];
    #pragma unroll
    for (int r = 0; r < 4; ++r) { m_[r] = -INFINITY; l_[r] = 0.f; }

    const int sr = tid >> 2, sc = (tid & 3) * 16;
    const bf16* kgb = ki  + (size_t)(b * 4 + kv) * 2048 * 64;
    const bf16* vgb = vti + (size_t)(b * 4 + kv) * 64 * 2048;

    const int kb_lo = (qb > 6) ? (qb - 6) : 0;
    {
        const bf16* kp = kgb + (size_t)(kb_lo * 64 + sr) * 64 + sc;
        const bf16* vp = vgb + (size_t)sr * 2048 + kb_lo * 64 + sc;
        *(bf16x8*)(&Ks[0][sr * 72 + sc])     = *(const bf16x8*)(kp);
        *(bf16x8*)(&Ks[0][sr * 72 + sc + 8]) = *(const bf16x8*)(kp + 8);
        *(bf16x8*)(&Vs[0][sr * 72 + sc])     = *(const bf16x8*)(vp);
        *(bf16x8*)(&Vs[0][sr * 72 + sc + 8]) = *(const bf16x8*)(vp + 8);
    }
    __syncthreads();

    for (int kb = kb_lo; kb <= qb; ++kb) {
        const int p = (kb - kb_lo) & 1;
        const int k0 = kb * 64;

        bf16x8 rk0, rk1, rv0, rv1;
        if (kb < qb) {
            const bf16* kp = kgb + (size_t)(k0 + 64 + sr) * 64 + sc;
            const bf16* vp = vgb + (size_t)sr * 2048 + k0 + 64 + sc;
            rk0 = *(const bf16x8*)(kp);
            rk1 = *(const bf16x8*)(kp + 8);
            rv0 = *(const bf16x8*)(vp);
            rv1 = *(const bf16x8*)(vp + 8);
        }

        f32x4 sacc[4];
        #pragma unroll
        for (int kt = 0; kt < 4; ++kt) {
            bf16x8 kf0 = *(const bf16x8*)(&Ks[p][(kt * 16 + lm) * 72 + lg * 8]);
            bf16x8 kf1 = *(const bf16x8*)(&Ks[p][(kt * 16 + lm) * 72 + 32 + lg * 8]);
            f32x4 z = {0.f, 0.f, 0.f, 0.f};
            z = MFMA16(qf0, kf0, z);
            sacc[kt] = MFMA16(qf1, kf1, z);
        }

        float pmax[4] = {-INFINITY, -INFINITY, -INFINITY, -INFINITY};
        #pragma unroll
        for (int kt = 0; kt < 4; ++kt)
            #pragma unroll
            for (int r = 0; r < 4; ++r) {
                int kgl = k0 + kt * 16 + lm;
                int qgl = q0 + w * 16 + lg * 4 + r;
                bool ok = (kgl <= qgl) && (kgl > qgl - 384);
                float s = ok ? sacc[kt][r] * SCL2 : -INFINITY;   // log2-space score
                sacc[kt][r] = s;
                pmax[r] = fmaxf(pmax[r], s);
            }
        #pragma unroll
        for (int r = 0; r < 4; ++r) {
            float t = pmax[r];
            t = fmaxf(t, __shfl_xor(t, 1));
            t = fmaxf(t, __shfl_xor(t, 2));
            t = fmaxf(t, __shfl_xor(t, 4));
            t = fmaxf(t, __shfl_xor(t, 8));
            pmax[r] = t;
        }

        #pragma unroll
        for (int r = 0; r < 4; ++r) {
            float mnew = fmaxf(m_[r], pmax[r]);
            float scale, rs = 0.f, pv[4];
            if (mnew > -INFINITY) {
                scale = exp2f(m_[r] - mnew);
                #pragma unroll
                for (int kt = 0; kt < 4; ++kt) { pv[kt] = exp2f(sacc[kt][r] - mnew); rs += pv[kt]; }
            } else {
                scale = 1.f;
                #pragma unroll
                for (int kt = 0; kt < 4; ++kt) pv[kt] = 0.f;
            }
            m_[r] = mnew;
            rs += __shfl_xor(rs, 1);
            rs += __shfl_xor(rs, 2);
            rs += __shfl_xor(rs, 4);
            rs += __shfl_xor(rs, 8);
            l_[r] = l_[r] * scale + rs;
            #pragma unroll
            for (int dt = 0; dt < 4; ++dt) oacc[dt][r] *= scale;
            #pragma unroll
            for (int kt = 0; kt < 4; ++kt)
                Ps[(w * 16 + lg * 4 + r) * 72 + kt * 16 + lm] = __float2bfloat16(pv[kt]);
        }

        bf16x8 pf0 = *(const bf16x8*)(&Ps[(w * 16 + lm) * 72 + lg * 8]);
        bf16x8 pf1 = *(const bf16x8*)(&Ps[(w * 16 + lm) * 72 + 32 + lg * 8]);
        #pragma unroll
        for (int dt = 0; dt < 4; ++dt) {
            bf16x8 vf0 = *(const bf16x8*)(&Vs[p][(dt * 16 + lm) * 72 + lg * 8]);
            bf16x8 vf1 = *(const bf16x8*)(&Vs[p][(dt * 16 + lm) * 72 + 32 + lg * 8]);
            oacc[dt] = MFMA16(pf0, vf0, oacc[dt]);
            oacc[dt] = MFMA16(pf1, vf1, oacc[dt]);
        }

        if (kb < qb) {
            __syncthreads();
            *(bf16x8*)(&Ks[p ^ 1][sr * 72 + sc])     = rk0;
            *(bf16x8*)(&Ks[p ^ 1][sr * 72 + sc + 8]) = rk1;
            *(bf16x8*)(&Vs[p ^ 1][sr * 72 + sc])     = rv0;
            *(bf16x8*)(&Vs[p ^ 1][sr * 72 + sc + 8]) = rv1;
            __syncthreads();
        }
    }

    #pragma unroll
    for (int r = 0; r < 4; ++r) {
        float inv = 1.f / l_[r];
        bf16* dst = ao + ((size_t)(b * 2048 + q0 + w * 16 + lg * 4 + r)) * 768 + h * 64;
        #pragma unroll
        for (int dt = 0; dt < 4; ++dt)
            dst[dt * 16 + lm] = __float2bfloat16(oacc[dt][r] * inv);
    }
}

// ================= Kernel 3: MFMA output projection (BM=128, bf16 in, fp32 out) ==
__global__ __launch_bounds__(256) void k_oproj(
    const bf16* __restrict__ A, const bf16* __restrict__ W, float* __restrict__ out)
{
    __shared__ bf16 As[2][128 * 72];
    __shared__ bf16 Bs[2][64 * 72];
    const int tid = threadIdx.x;
    const int w = tid >> 6, l = tid & 63;
    const int lm = l & 15, lg = l >> 4;
    const int m0 = blockIdx.x * 128, n0 = blockIdx.y * 64;

    const int sr = tid >> 2, sc = (tid & 3) * 16;
    const bf16* aptr0 = A + (size_t)(m0 + sr) * 768 + sc;
    const bf16* aptr1 = A + (size_t)(m0 + 64 + sr) * 768 + sc;
    const bf16* bptr  = W + (size_t)(n0 + sr) * 768 + sc;

    bf16x8 ra[4], rb[2];
    ra[0] = *(const bf16x8*)(aptr0);
    ra[1] = *(const bf16x8*)(aptr0 + 8);
    ra[2] = *(const bf16x8*)(aptr1);
    ra[3] = *(const bf16x8*)(aptr1 + 8);
    rb[0] = *(const bf16x8*)(bptr);
    rb[1] = *(const bf16x8*)(bptr + 8);
    *(bf16x8*)(&As[0][sr * 72 + sc])            = ra[0];
    *(bf16x8*)(&As[0][sr * 72 + sc + 8])        = ra[1];
    *(bf16x8*)(&As[0][(64 + sr) * 72 + sc])     = ra[2];
    *(bf16x8*)(&As[0][(64 + sr) * 72 + sc + 8]) = ra[3];
    *(bf16x8*)(&Bs[0][sr * 72 + sc])            = rb[0];
    *(bf16x8*)(&Bs[0][sr * 72 + sc + 8])        = rb[1];
    __syncthreads();

    f32x4 acc[2][4] = {};
    for (int t = 0; t < 12; ++t) {
        const int p = t & 1;
        if (t < 11) {
            const int off = (t + 1) * 64;
            ra[0] = *(const bf16x8*)(aptr0 + off);
            ra[1] = *(const bf16x8*)(aptr0 + off + 8);
            ra[2] = *(const bf16x8*)(aptr1 + off);
            ra[3] = *(const bf16x8*)(aptr1 + off + 8);
            rb[0] = *(const bf16x8*)(bptr + off);
            rb[1] = *(const bf16x8*)(bptr + off + 8);
        }
        #pragma unroll
        for (int kk = 0; kk < 2; ++kk) {
            bf16x8 a0 = *(const bf16x8*)(&As[p][(w * 32 + lm) * 72 + kk * 32 + lg * 8]);
            bf16x8 a1 = *(const bf16x8*)(&As[p][(w * 32 + 16 + lm) * 72 + kk * 32 + lg * 8]);
            #pragma unroll
            for (int ct = 0; ct < 4; ++ct) {
                bf16x8 bfr = *(const bf16x8*)(&Bs[p][(ct * 16 + lm) * 72 + kk * 32 + lg * 8]);
                acc[0][ct] = MFMA16(a0, bfr, acc[0][ct]);
                acc[1][ct] = MFMA16(a1, bfr, acc[1][ct]);
            }
        }
        if (t < 11) {
            __syncthreads();
            *(bf16x8*)(&As[p ^ 1][sr * 72 + sc])            = ra[0];
            *(bf16x8*)(&As[p ^ 1][sr * 72 + sc + 8])        = ra[1];
            *(bf16x8*)(&As[p ^ 1][(64 + sr) * 72 + sc])     = ra[2];
            *(bf16x8*)(&As[p ^ 1][(64 + sr) * 72 + sc + 8]) = ra[3];
            *(bf16x8*)(&Bs[p ^ 1][sr * 72 + sc])            = rb[0];
            *(bf16x8*)(&Bs[p ^ 1][sr * 72 + sc + 8])        = rb[1];
            __syncthreads();
        }
    }

    #pragma unroll
    for (int m = 0; m < 2; ++m)
        #pragma unroll
        for (int r = 0; r < 4; ++r) {
            float* dst = out + (size_t)(m0 + w * 32 + m * 16 + lg * 4 + r) * 768 + n0;
            #pragma unroll
            for (int ct = 0; ct < 4; ++ct)
                dst[ct * 16 + lm] = acc[m][ct][r];
        }
}

extern "C" void kernel_launch(void* const* d_in, const int* in_sizes, int n_in,
                              void* d_out, int out_size, void* d_ws, size_t ws_size,
                              hipStream_t stream) {
    const float* hs  = (const float*)d_in[0];
    const float* qw  = (const float*)d_in[1];
    const float* kw  = (const float*)d_in[2];
    const float* vw  = (const float*)d_in[3];
    const float* ow  = (const float*)d_in[4];
    const float* qln = (const float*)d_in[5];
    const float* kln = (const float*)d_in[6];
    float* out = (float*)d_out;

    float2* tab  = (float2*)d_ws;
    bf16*   q_ws = (bf16*)(tab + 65536);
    bf16*   k_ws = q_ws + 3145728;
    bf16*   vt_ws= k_ws + 1048576;
    bf16*   x_ws = vt_ws + 1048576;    // hsb during k_qkv, attn output after
    bf16*   qwb  = x_ws + 3145728;
    bf16*   kwb  = qwb + 589824;
    bf16*   vwb  = kwb + 196608;
    bf16*   owb  = vwb + 196608;

    k_prep<<<dim3(4864), 256, 0, stream>>>(hs, qw, kw, vw, ow, x_ws, qwb, kwb, vwb, owb, tab);
    k_qkv<<<dim3(32, 20, 1), 256, 0, stream>>>(x_ws, qwb, kwb, vwb, qln, kln, tab, q_ws, k_ws, vt_ws);
    k_attn<<<dim3(32, 12, 2), 256, 0, stream>>>(q_ws, k_ws, vt_ws, x_ws);
    k_oproj<<<dim3(32, 12, 1), 256, 0, stream>>>(x_ws, owb, out);
}